// Round 10
// baseline (223.751 us; speedup 1.0000x reference)
//
#include <hip/hip_runtime.h>
#include <hip/hip_bf16.h>
#include <stdint.h>
#include <math.h>

// B=2, S=2048, D=1024, H=16, HD=64.  M = 4096 tokens.
// All matmuls bf16 MFMA 16x16x32, f32 accumulate.
// R10: qkv GEMM re-tiled BM=64 (1664 blocks = 6.5/CU, kills the 3.25->4
// load-imbalance tail; 24 KB LDS -> ~5-6 blocks/CU resident). XCD regions
// rebuilt for the 26x64 grid. attn (R9, fused MLP2) and out-proj unchanged.

typedef __attribute__((ext_vector_type(8))) short short8;
typedef __attribute__((ext_vector_type(8))) unsigned short ushort8;
typedef __attribute__((ext_vector_type(4))) float floatx4;

#define MFMA16(a, b, c) __builtin_amdgcn_mfma_f32_16x16x32_bf16(a, b, c, 0, 0, 0)

__device__ __forceinline__ unsigned short f2bf(float f) {
    union { float f; uint32_t u; } v; v.f = f;
    uint32_t r = v.u + 0x7fffu + ((v.u >> 16) & 1u);   // RNE
    return (unsigned short)(r >> 16);
}
__device__ __forceinline__ float bf2f(unsigned short s) {
    union { uint32_t u; float f; } v; v.u = ((uint32_t)s) << 16;
    return v.f;
}
// packed f32x2 -> bf16x2 (v_cvt_pk_bf16_f32), RNE
__device__ __forceinline__ uint32_t pk2(float a, float b) {
    __hip_bfloat162 t = __float22bfloat162_rn(make_float2(a, b));
    uint32_t u; __builtin_memcpy(&u, &t, 4); return u;
}

typedef const __attribute__((address_space(1))) void gvoid_t;
typedef __attribute__((address_space(3))) void lvoid_t;
__device__ __forceinline__ void gld16(const void* g, void* l) {
    __builtin_amdgcn_global_load_lds((gvoid_t*)g, (lvoid_t*)l, 16, 0, 0);
}

// ---------------------------------------------------------------------------
// BN=128 GEMM core, BM templated (128: waves 2x2 of 64x64; 64: 2x2 of 32x64).
// BK=32, dbuf LDS. Swizzle slot = chunk ^ ((row>>1)&3).
// vt != nullptr: V epilogue writes transposed per head into Vt[bh,hd,s].
// ---------------------------------------------------------------------------
template<int BM, bool OUTBF>
__device__ __forceinline__ void gemm_coreN128(const unsigned short* __restrict__ A,
                                              const unsigned short* __restrict__ W,
                                              const float* __restrict__ bias,
                                              void* __restrict__ C,
                                              int N, int K, int bm, int bn,
                                              bool relu, float osc,
                                              unsigned short* __restrict__ vt)
{
    constexpr int MT = BM / 32;            // m-tiles per wave
    constexpr int AI = BM / 16;            // A staging instrs
    constexpr int SU = (AI + 8) / 4;       // instrs per wave
    __shared__ __align__(16) unsigned short As[2][BM][32];
    __shared__ __align__(16) unsigned short Ws[2][128][32];

    const int tid  = threadIdx.x;
    const int w    = tid >> 6, lane = tid & 63;
    const int ln   = lane & 15, quad = lane >> 4;
    const int wm   = (w >> 1) * (BM / 2), wn = (w & 1) * 64;

    floatx4 acc[MT][4] = {};

    auto stage = [&](int k0, int bb) {
        #pragma unroll
        for (int i = 0; i < SU; i++) {
            const int t = w * SU + i;
            if (t < AI) {
                const int r0  = t * 16;
                const int row = r0 + (lane >> 2);
                const int c   = (lane & 3) ^ ((row >> 1) & 3);
                gld16(&A[(size_t)(bm + row) * K + k0 + c * 8], &As[bb][r0][0]);
            } else if (t < AI + 8) {
                const int r0  = (t - AI) * 16;
                const int row = r0 + (lane >> 2);
                const int c   = (lane & 3) ^ ((row >> 1) & 3);
                gld16(&W[(size_t)(bn + row) * K + k0 + c * 8], &Ws[bb][r0][0]);
            }
        }
    };

    stage(0, 0);

    const int KI = K >> 5;
    for (int ki = 0; ki < KI; ki++) {
        const int bb = ki & 1;
        __syncthreads();
        if (ki + 1 < KI) stage((ki + 1) << 5, bb ^ 1);

        short8 af[MT], bf[4];
        #pragma unroll
        for (int mt = 0; mt < MT; mt++) {
            const int row = wm + mt * 16 + ln;
            af[mt] = *(const short8*)&As[bb][row][(quad ^ ((row >> 1) & 3)) * 8];
        }
        #pragma unroll
        for (int nt = 0; nt < 4; nt++) {
            const int row = wn + nt * 16 + ln;
            bf[nt] = *(const short8*)&Ws[bb][row][(quad ^ ((row >> 1) & 3)) * 8];
        }
        #pragma unroll
        for (int mt = 0; mt < MT; mt++)
            #pragma unroll
            for (int nt = 0; nt < 4; nt++)
                acc[mt][nt] = MFMA16(af[mt], bf[nt], acc[mt][nt]);
    }

    float bv[4];
    #pragma unroll
    for (int nt = 0; nt < 4; nt++) bv[nt] = bias[bn + wn + nt * 16 + ln];

    if (vt != nullptr) {
        #pragma unroll
        for (int mt = 0; mt < MT; mt++) {
            const int rowg = bm + wm + mt * 16 + quad * 4;   // +r consecutive s
            const int b = rowg >> 11, s = rowg & 2047;
            #pragma unroll
            for (int nt = 0; nt < 4; nt++) {
                const int n = bn + wn + nt * 16 + ln;
                const int h = n >> 6, hd = n & 63;
                uint2 pk;
                pk.x = pk2(acc[mt][nt][0] + bv[nt], acc[mt][nt][1] + bv[nt]);
                pk.y = pk2(acc[mt][nt][2] + bv[nt], acc[mt][nt][3] + bv[nt]);
                *(uint2*)&vt[((size_t)(b * 16 + h) * 64 + hd) * 2048 + s] = pk;
            }
        }
        return;
    }

    #pragma unroll
    for (int mt = 0; mt < MT; mt++) {
        #pragma unroll
        for (int nt = 0; nt < 4; nt++) {
            #pragma unroll
            for (int r = 0; r < 4; r++) {
                float v = (acc[mt][nt][r] + bv[nt]) * osc;
                if (relu) v = fmaxf(v, 0.f);
                const size_t row = (size_t)bm + wm + mt * 16 + quad * 4 + r;
                const size_t col = (size_t)bn + wn + nt * 16 + ln;
                if (OUTBF) ((unsigned short*)C)[row * N + col] = f2bf(v);
                else       ((float*)C)[row * N + col] = v;
            }
        }
    }
}

// ---------------------------------------------------------------------------
// BN=64 GEMM core, BK=64: BM=128, dbuf. 4 waves 4x1 of 32x64. (out-proj)
// ---------------------------------------------------------------------------
template<bool OUTBF>
__device__ __forceinline__ void gemm_core64(const unsigned short* __restrict__ A,
                                            const unsigned short* __restrict__ W,
                                            const float* __restrict__ bias,
                                            void* __restrict__ C,
                                            int N, int K, int bm, int bn)
{
    __shared__ __align__(16) unsigned short As[2][128][64];   // 32 KB
    __shared__ __align__(16) unsigned short Ws[2][64][64];    // 16 KB

    const int tid  = threadIdx.x;
    const int w    = tid >> 6, lane = tid & 63;
    const int ln   = lane & 15, quad = lane >> 4;
    const int wm   = w * 32;

    floatx4 acc[2][4] = {};

    auto stage = [&](int k0, int bb) {
        #pragma unroll
        for (int i = 0; i < 6; i++) {
            const int t = w * 6 + i;
            if (t < 16) {        // A: 16 instrs x 8 rows
                const int row = t * 8 + (lane >> 3);
                const int c   = (lane & 7) ^ (row & 7);
                gld16(&A[(size_t)(bm + row) * K + k0 + c * 8], &As[bb][t * 8][0]);
            } else {             // W: 8 instrs x 8 rows
                const int tv  = t - 16;
                const int row = tv * 8 + (lane >> 3);
                const int c   = (lane & 7) ^ (row & 7);
                gld16(&W[(size_t)(bn + row) * K + k0 + c * 8], &Ws[bb][tv * 8][0]);
            }
        }
    };

    stage(0, 0);

    const int KI = K >> 6;
    for (int ki = 0; ki < KI; ki++) {
        const int bb = ki & 1;
        __syncthreads();
        if (ki + 1 < KI) stage((ki + 1) << 6, bb ^ 1);

        short8 af[2][2], bf[4][2];
        #pragma unroll
        for (int mt = 0; mt < 2; mt++) {
            const int row = wm + mt * 16 + ln;
            #pragma unroll
            for (int s = 0; s < 2; s++)
                af[mt][s] = *(const short8*)&As[bb][row][(((s * 4 + quad)) ^ (row & 7)) * 8];
        }
        #pragma unroll
        for (int nt = 0; nt < 4; nt++) {
            const int row = nt * 16 + ln;
            #pragma unroll
            for (int s = 0; s < 2; s++)
                bf[nt][s] = *(const short8*)&Ws[bb][row][(((s * 4 + quad)) ^ (row & 7)) * 8];
        }
        #pragma unroll
        for (int s = 0; s < 2; s++)
            #pragma unroll
            for (int mt = 0; mt < 2; mt++)
                #pragma unroll
                for (int nt = 0; nt < 4; nt++)
                    acc[mt][nt] = MFMA16(af[mt][s], bf[nt][s], acc[mt][nt]);
    }

    float bv[4];
    #pragma unroll
    for (int nt = 0; nt < 4; nt++) bv[nt] = bias[bn + nt * 16 + ln];

    #pragma unroll
    for (int mt = 0; mt < 2; mt++) {
        #pragma unroll
        for (int nt = 0; nt < 4; nt++) {
            #pragma unroll
            for (int r = 0; r < 4; r++) {
                const float v = acc[mt][nt][r] + bv[nt];
                const size_t row = (size_t)bm + wm + mt * 16 + quad * 4 + r;
                const size_t col = (size_t)bn + nt * 16 + ln;
                if (OUTBF) ((unsigned short*)C)[row * N + col] = f2bf(v);
                else       ((float*)C)[row * N + col] = v;
            }
        }
    }
}

#define QSCALE (0.125f * 1.44269504088896f)   // HD^-0.5 * log2(e)

// R10: BM=64, grid 1664 (6.5 blocks/CU). XCD regions: 16 regions of
// 13bx x 8bm; XCD g gets regions with same bx band (g and g+8).
__global__ __launch_bounds__(256) void qkv_mlp1_gemm(
    const unsigned short* __restrict__ A,
    const unsigned short* __restrict__ Wq, const unsigned short* __restrict__ Wk,
    const unsigned short* __restrict__ Wv, const unsigned short* __restrict__ Wm1,
    const float* __restrict__ bq, const float* __restrict__ bk,
    const float* __restrict__ bv, const float* __restrict__ bm1,
    unsigned short* __restrict__ Qo, unsigned short* __restrict__ Ko,
    unsigned short* __restrict__ Vt, unsigned short* __restrict__ Ho)
{
    const int flat = blockIdx.x;             // [0,1664)
    const int g  = flat & 7;                 // XCD (round-robin heuristic)
    const int s  = flat >> 3;                // [0,208)
    const int h8 = (s >= 104) ? 1 : 0;
    const int s2 = s - 104 * h8;             // [0,104)
    const int rx = g & 1;
    const int ry = (g >> 1) + 4 * h8;        // [0,8)
    const int bx = rx * 13 + (s2 % 13);      // [0,26)
    const int bm = (ry * 8 + (s2 / 13)) * 64;// [0,4096)

    const unsigned short* W; const float* bias; unsigned short* C = nullptr;
    unsigned short* vt = nullptr;
    int N, bn; bool relu = false; float osc = 1.f;
    if (bx < 8)       { W = Wq;  bias = bq;  C = Qo; N = 1024; bn = bx * 128; osc = QSCALE; }
    else if (bx < 16) { W = Wk;  bias = bk;  C = Ko; N = 1024; bn = (bx - 8) * 128; }
    else if (bx < 24) { W = Wv;  bias = bv;  vt = Vt; N = 1024; bn = (bx - 16) * 128; }
    else              { W = Wm1; bias = bm1; C = Ho; N = 256;  bn = (bx - 24) * 128; relu = true; }
    gemm_coreN128<64, true>(A, W, bias, C, N, 1024, bm, bn, relu, osc, vt);
}

template<bool OUTBF>
__global__ __launch_bounds__(256) void gemm_bn64(const unsigned short* __restrict__ A,
                                                 const unsigned short* __restrict__ W,
                                                 const float* __restrict__ bias,
                                                 void* __restrict__ C, int N, int K)
{
    // XCD swizzle: 512 blocks -> 8 regions of 8 bx x 8 bm.
    const int flat = blockIdx.x + 16 * blockIdx.y;
    const int g = flat & 7, s = flat >> 3;           // s in [0,64)
    const int bx = (g & 1) * 8 + (s & 7);
    const int bm = ((g >> 1) * 8 + (s >> 3)) * 128;
    gemm_core64<OUTBF>(A, W, bias, C, N, K, bm, bx * 64);
}

// ---------------------------------------------------------------------------
// MFMA flash attention + FUSED MLP2 + neuromodulation epilogue. (R9 design)
// ---------------------------------------------------------------------------
__global__ __launch_bounds__(256) void attn_mfma(const unsigned short* __restrict__ Qg,
                                                 const unsigned short* __restrict__ Kg,
                                                 const unsigned short* __restrict__ Vtg,
                                                 const unsigned short* __restrict__ Hmg,
                                                 const unsigned short* __restrict__ Wm2g,
                                                 const float* __restrict__ bm2,
                                                 unsigned short* __restrict__ Yg,
                                                 const float* __restrict__ dop,
                                                 const float* __restrict__ ser,
                                                 const float* __restrict__ nor,
                                                 const float* __restrict__ ach,
                                                 const float* __restrict__ asc,
                                                 const float* __restrict__ abi)
{
    __shared__ __align__(16) unsigned short Ks[2][128][64];   // 32 KB
    __shared__ __align__(16) unsigned short Vs[2][64][128];   // 32 KB
    __shared__ __align__(16) unsigned short Ps[4][2][16][64]; // 16 KB

    const int tid = threadIdx.x;
    const int w   = tid >> 6, lane = tid & 63;
    const int ln  = lane & 15, quad = lane >> 4;
    const int h   = blockIdx.x, qt = blockIdx.y, b = blockIdx.z;

    const size_t kbase = (size_t)b * 2048 * 1024 + h * 64;     // K [b,s,d]
    const size_t vbase = (size_t)(b * 16 + h) * 64 * 2048;     // Vt [bh,hd,s]
    const size_t qtblk = (size_t)b * 2048 + qt * 128;          // block row base

    // Q B-frags (loop-invariant, pre-scaled): B[n=ln][k=quad*8+j]
    const size_t qrowbase = qtblk + w * 32;
    short8 qf[2][2];
    #pragma unroll
    for (int q2 = 0; q2 < 2; q2++) {
        const unsigned short* qp = Qg + (qrowbase + q2 * 16 + ln) * 1024 + h * 64;
        qf[q2][0] = *(const short8*)&qp[quad * 8];
        qf[q2][1] = *(const short8*)&qp[32 + quad * 8];
    }

    // constant bf16 1.0 B-frag for the lsum column-MFMA
    short8 ones8;
    #pragma unroll
    for (int j = 0; j < 8; j++) ones8[j] = (short)0x3F80;

    floatx4 o[2][4] = {};
    floatx4 ls[2] = {};

    auto stage = [&](int kc, int bb) {
        #pragma unroll
        for (int i = 0; i < 8; i++) {
            const int t = w * 8 + i;
            if (t < 16) {       // K rows: 8 rows x 8 chunks per instr
                const int R = t * 8 + (lane >> 3);
                const int c = (lane & 7) ^ (R & 7);
                gld16(&Kg[kbase + (size_t)(kc * 128 + R) * 1024 + c * 8], &Ks[bb][t * 8][0]);
            } else {            // V^T rows: 4 rows x 16 chunks per instr
                const int tv = t - 16;
                const int R  = tv * 4 + (lane >> 4);
                const int c  = (lane & 15) ^ (R & 15);
                gld16(&Vtg[vbase + (size_t)R * 2048 + kc * 128 + c * 8], &Vs[bb][tv * 4][0]);
            }
        }
    };

    stage(0, 0);

    for (int kc = 0; kc < 16; kc++) {
        const int bb = kc & 1;
        __syncthreads();
        if (kc + 1 < 16) stage(kc + 1, bb ^ 1);

        #pragma unroll
        for (int half = 0; half < 2; half++) {
            // K-frags for this half (shared across both q-tiles)
            short8 kf[4][2];
            #pragma unroll
            for (int mt = 0; mt < 4; mt++) {
                const int row = half * 64 + mt * 16 + ln;
                kf[mt][0] = *(const short8*)&Ks[bb][row][((0 + quad) ^ (ln & 7)) * 8];
                kf[mt][1] = *(const short8*)&Ks[bb][row][((4 + quad) ^ (ln & 7)) * 8];
            }

            // ---- scores S^T (A=K, B=Q) + exp2 + packed P store ----
            #pragma unroll
            for (int q2 = 0; q2 < 2; q2++) {
                floatx4 sc[4];
                #pragma unroll
                for (int mt = 0; mt < 4; mt++) {
                    floatx4 z = {};
                    z = MFMA16(kf[mt][0], qf[q2][0], z);
                    z = MFMA16(kf[mt][1], qf[q2][1], z);
                    sc[mt] = z;
                }
                #pragma unroll
                for (int mt = 0; mt < 4; mt++) {
                    const float p0 = __builtin_amdgcn_exp2f(sc[mt][0]);
                    const float p1 = __builtin_amdgcn_exp2f(sc[mt][1]);
                    const float p2 = __builtin_amdgcn_exp2f(sc[mt][2]);
                    const float p3 = __builtin_amdgcn_exp2f(sc[mt][3]);
                    uint2 pk; pk.x = pk2(p0, p1); pk.y = pk2(p2, p3);
                    const int c2 = (mt * 2 + (quad >> 1)) ^ (ln & 7);
                    *(uint2*)((char*)&Ps[w][q2][ln][0] + c2 * 16 + (quad & 1) * 8) = pk;
                }
            }

            // ---- PV: A = P (m=q), B = V (n=hd); +ones column for lsum ----
            short8 pf[2][2];
            #pragma unroll
            for (int q2 = 0; q2 < 2; q2++)
                #pragma unroll
                for (int ks = 0; ks < 2; ks++) {
                    const int c2 = (ks * 4 + quad) ^ (ln & 7);
                    pf[q2][ks] = *(const short8*)((char*)&Ps[w][q2][ln][0] + c2 * 16);
                }
            #pragma unroll
            for (int q2 = 0; q2 < 2; q2++)
                #pragma unroll
                for (int ks = 0; ks < 2; ks++)
                    ls[q2] = MFMA16(pf[q2][ks], ones8, ls[q2]);
            #pragma unroll
            for (int ntv = 0; ntv < 4; ntv++) {
                const int vrow = ntv * 16 + ln;
                #pragma unroll
                for (int ks = 0; ks < 2; ks++) {
                    const int c2 = (half * 8 + ks * 4 + quad) ^ (ln & 15);
                    const short8 vf = *(const short8*)&Vs[bb][vrow][c2 * 8];
                    o[0][ntv] = MFMA16(pf[0][ks], vf, o[0][ntv]);
                    o[1][ntv] = MFMA16(pf[1][ks], vf, o[1][ntv]);
                }
            }
        }
    }

    // ================= fused MLP2: Mod = Hm @ Wm2^T + bm2 =================
    unsigned short* HmS = &Ks[0][0][0];   // [128][128] view, 32 KB
    unsigned short* WmS = &Vs[0][0][0];   // [64][256] view, 32 KB

    __syncthreads();    // everyone done reading Ks/Vs from the main loop

    // stage Wm2[h*64 .. +64][0..256) : 32 instrs x 1KB (2 rows each)
    #pragma unroll
    for (int i = 0; i < 8; i++) {
        const int t  = w * 8 + i;
        const int r0 = t * 2;
        const int row = r0 + (lane >> 5);
        const int sl  = lane & 31;
        gld16(&Wm2g[(size_t)(h * 64 + row) * 256 + ((sl ^ (row & 7)) * 8)],
              &WmS[r0 * 256]);
    }
    // stage Hm[qtblk..+128][0..128) round 0 : 32 instrs x 1KB (4 rows each)
    #pragma unroll
    for (int i = 0; i < 8; i++) {
        const int t  = w * 8 + i;
        const int r0 = t * 4;
        const int row = r0 + (lane >> 4);
        const int sl  = lane & 15;
        gld16(&Hmg[(qtblk + row) * 256 + ((sl ^ (row & 7)) * 8)],
              &HmS[r0 * 128]);
    }

    floatx4 mo[2][4] = {};
    #pragma unroll
    for (int round = 0; round < 2; round++) {
        __syncthreads();   // staged data visible (and, for r1, reads done)
        #pragma unroll
        for (int ks = 0; ks < 4; ks++) {
            short8 af[2];
            #pragma unroll
            for (int q2 = 0; q2 < 2; q2++) {
                const int row = w * 32 + q2 * 16 + ln;
                af[q2] = *(const short8*)&HmS[row * 128 + (((ks * 4 + quad) ^ (ln & 7)) * 8)];
            }
            #pragma unroll
            for (int ntv = 0; ntv < 4; ntv++) {
                const int row = ntv * 16 + ln;
                const int ks8 = round * 4 + ks;
                const short8 bf = *(const short8*)&WmS[row * 256 + (((ks8 * 4 + quad) ^ (ln & 7)) * 8)];
                mo[0][ntv] = MFMA16(af[0], bf, mo[0][ntv]);
                mo[1][ntv] = MFMA16(af[1], bf, mo[1][ntv]);
            }
        }
        if (round == 0) {
            __syncthreads();   // all reads of HmS round-0 done
            #pragma unroll
            for (int i = 0; i < 8; i++) {
                const int t  = w * 8 + i;
                const int r0 = t * 4;
                const int row = r0 + (lane >> 4);
                const int sl  = lane & 15;
                gld16(&Hmg[(qtblk + row) * 256 + 128 + ((sl ^ (row & 7)) * 8)],
                      &HmS[r0 * 128]);
            }
        }
    }

    // ======================= combine + store =======================
    const float gate = 0.25f * (dop[0] + ser[0] + nor[0] + ach[0]);
    const float scb = asc[0], bib = abi[0];
    float bm2v[4];
    #pragma unroll
    for (int ntv = 0; ntv < 4; ntv++) bm2v[ntv] = bm2[h * 64 + ntv * 16 + ln];

    #pragma unroll
    for (int q2 = 0; q2 < 2; q2++) {
        #pragma unroll
        for (int r = 0; r < 4; r++) {
            const float inv = 1.f / ls[q2][r];      // lsum for row quad*4+r
            const size_t row = qrowbase + q2 * 16 + quad * 4 + r;
            #pragma unroll
            for (int ntv = 0; ntv < 4; ntv++) {
                const size_t col = (size_t)h * 64 + ntv * 16 + ln;
                const float x  = o[q2][ntv][r] * inv;
                const float m  = mo[q2][ntv][r] + bm2v[ntv];
                const float y  = (x * scb + bib) * (1.f + m * gate);
                Yg[row * 1024 + col] = f2bf(y);
            }
        }
    }
}

// ---------------------------------------------------------------------------
// Fused f32 -> bf16 casts (query + 6 weights), 8 elems/thread, packed cvt.
// ---------------------------------------------------------------------------
__global__ __launch_bounds__(256) void fused_cast(
    const float* __restrict__ q,   const float* __restrict__ wq,
    const float* __restrict__ wk,  const float* __restrict__ wv,
    const float* __restrict__ wo,  const float* __restrict__ wm1,
    const float* __restrict__ wm2,
    unsigned short* __restrict__ dq,  unsigned short* __restrict__ dwq,
    unsigned short* __restrict__ dwk, unsigned short* __restrict__ dwv,
    unsigned short* __restrict__ dwo, unsigned short* __restrict__ dwm1,
    unsigned short* __restrict__ dwm2)
{
    const size_t u = (size_t)blockIdx.x * 256 + threadIdx.x;
    const float* src; unsigned short* dst; size_t off;
    if      (u <  524288) { src = q;   dst = dq;   off = u; }
    else if (u <  655360) { src = wq;  dst = dwq;  off = u - 524288; }
    else if (u <  786432) { src = wk;  dst = dwk;  off = u - 655360; }
    else if (u <  917504) { src = wv;  dst = dwv;  off = u - 786432; }
    else if (u < 1048576) { src = wo;  dst = dwo;  off = u - 917504; }
    else if (u < 1081344) { src = wm1; dst = dwm1; off = u - 1048576; }
    else                  { src = wm2; dst = dwm2; off = u - 1081344; }
    const float4* p = (const float4*)src + off * 2;
    const float4 a = p[0], c = p[1];
    uint4 o;
    o.x = pk2(a.x, a.y); o.y = pk2(a.z, a.w);
    o.z = pk2(c.x, c.y); o.w = pk2(c.z, c.w);
    *(uint4*)&dst[off * 8] = o;
}

// ---------------------------------------------------------------------------
extern "C" void kernel_launch(void* const* d_in, const int* in_sizes, int n_in,
                              void* d_out, int out_size, void* d_ws, size_t ws_size,
                              hipStream_t stream)
{
    const float* query = (const float*)d_in[0];
    const float* Wq  = (const float*)d_in[1];
    const float* bq  = (const float*)d_in[2];
    const float* Wk  = (const float*)d_in[3];
    const float* bk  = (const float*)d_in[4];
    const float* Wv  = (const float*)d_in[5];
    const float* bv  = (const float*)d_in[6];
    const float* Wo  = (const float*)d_in[7];
    const float* bo  = (const float*)d_in[8];
    const float* Wm1 = (const float*)d_in[9];
    const float* bm1 = (const float*)d_in[10];
    const float* Wm2 = (const float*)d_in[11];
    const float* bm2 = (const float*)d_in[12];
    const float* dop = (const float*)d_in[13];
    const float* ser = (const float*)d_in[14];
    const float* nor = (const float*)d_in[15];
    const float* ach = (const float*)d_in[16];
    const float* asc = (const float*)d_in[17];
    const float* abi = (const float*)d_in[18];

    char* ws = (char*)d_ws;
    const size_t MB = 1024 * 1024;
    unsigned short* Qry  = (unsigned short*)(ws);
    unsigned short* Wqb  = (unsigned short*)(ws + 8 * MB);
    unsigned short* Wkb  = (unsigned short*)(ws + 10 * MB);
    unsigned short* Wvb  = (unsigned short*)(ws + 12 * MB);
    unsigned short* Wob  = (unsigned short*)(ws + 14 * MB);
    unsigned short* Wm1b = (unsigned short*)(ws + 16 * MB);
    unsigned short* Wm2b = (unsigned short*)(ws + 16 * MB + 512 * 1024);
    unsigned short* Qb   = (unsigned short*)(ws + 17 * MB);
    unsigned short* Kb   = (unsigned short*)(ws + 25 * MB);
    unsigned short* Vt   = (unsigned short*)(ws + 41 * MB);
    unsigned short* Yb   = (unsigned short*)(ws + 49 * MB);
    unsigned short* Hm   = (unsigned short*)(ws + 57 * MB);

    // 1. all f32->bf16 casts
    fused_cast<<<4352, 256, 0, stream>>>(query, Wq, Wk, Wv, Wo, Wm1, Wm2,
                                         Qry, Wqb, Wkb, Wvb, Wob, Wm1b, Wm2b);

    // 2. fused QKV + MLP1 GEMM, BM=64 (Q pre-scaled; V transposed)
    qkv_mlp1_gemm<<<1664, 256, 0, stream>>>(
        Qry, Wqb, Wkb, Wvb, Wm1b, bq, bk, bv, bm1, Qb, Kb, Vt, Hm);

    // 3. attention + fused MLP2 + neuromodulation -> Yb  (h fastest: XCD pin)
    attn_mfma<<<dim3(16, 16, 2), 256, 0, stream>>>(Qb, Kb, Vt, Hm, Wm2b, bm2, Yb,
                                                   dop, ser, nor, ach, asc, abi);

    // 4. out = Yb @ Wo^T + bo (f32)
    gemm_bn64<false><<<dim3(16, 32), 256, 0, stream>>>(Yb, Wob, bo, d_out, 1024, 1024);
}